// Round 3
// baseline (421.327 us; speedup 1.0000x reference)
//
#include <hip/hip_runtime.h>
#include <math.h>

#define NB_ 512
#define B_ 32
#define H_ 16
#define D_ 576
#define KV_ 512
#define BS_ 128
#define STR 578                       // padded LDS stride; 578%32=2 -> hq/sq read phases spread, max 2-way
#define SCALE_ 0.07216878364870323f   // 192^-0.5

// Workspace as device globals: k1 fully writes before k2 reads, every call.
__device__ float g_o[NB_ * H_ * KV_];   // unscaled per-block output, 16.8 MB
__device__ float g_bm[NB_ * H_];        // per-block running max
__device__ float g_bs[NB_ * H_];        // per-block running sum

// One workgroup per block n. 256 threads = 4 waves; wave w owns heads 4w..4w+3.
// Fused single pass, outer-product logit tiling (4h x 4s x 36d per lane).
__global__ __launch_bounds__(256) void mla_block_kernel(
    const float* __restrict__ query,
    const float* __restrict__ key_cache,
    const float* __restrict__ block_bias,
    const int* __restrict__ block_list,
    const int* __restrict__ block_groups)
{
    __shared__ float q_s[H_ * STR];     // scaled q, 36992 B
    __shared__ float kt[16 * STR];      // current 16-row K chunk, 36992 B
    __shared__ float red[4 * 256];      // cross-wave logit partials, 4 KB
    __shared__ float p_s[H_ * 16];      // p[h][s16]
    __shared__ float alpha_s[H_];       // per-head rescale

    const int tid = threadIdx.x;
    const int n   = blockIdx.x;
    const int b   = block_groups[n];
    const float* K = key_cache + (long)block_list[n] * (BS_ * D_);
    const float* Q = query + (long)b * (H_ * D_);

    // ---- stage scaled q into padded LDS (16 rows x 144 float4) ----
#pragma unroll
    for (int i = 0; i < 9; ++i) {
        int flat = tid + 256 * i;           // 0..2303
        int row = flat / 144;
        int c4  = flat - row * 144;
        float4 v = *(const float4*)(Q + row * D_ + 4 * c4);
        v.x *= SCALE_; v.y *= SCALE_; v.z *= SCALE_; v.w *= SCALE_;
        *(float4*)(q_s + row * STR + 4 * c4) = v;
    }

    // owning-lane mapping (softmax / PV / output)
    const int hg  = tid >> 6;    // wave id -> heads 4hg..4hg+3
    const int sl  = tid & 63;
    const int h2  = sl >> 4;
    const int s16 = sl & 15;
    const int h   = 4 * hg + h2;

    // logit-compute mapping (outer-product tile)
    const int sq    = tid & 3;          // s-quad: s = 4*sq + jj
    const int hq    = (tid >> 2) & 3;   // h-quad: hh = 4*hq + i
    const int dgrp  = tid >> 4;         // 0..15, 36-float d-slice each
    const int dbase = dgrp * 36;

    float bias[8];
#pragma unroll
    for (int c = 0; c < 8; ++c) bias[c] = block_bias[n * BS_ + 16 * c + s16];

    float m_run = -1e30f;
    float l_run = 0.f;
    float4 oa0[4], oa1[4];
#pragma unroll
    for (int i = 0; i < 4; ++i) {
        oa0[i] = make_float4(0.f, 0.f, 0.f, 0.f);
        oa1[i] = make_float4(0.f, 0.f, 0.f, 0.f);
    }

    for (int sc8 = 0; sc8 < 8; ++sc8) {
        __syncthreads();   // prev chunk kt/p_s reads done; 1st iter: q_s staged
        // ---- stage 16 K rows (coalesced) ----
#pragma unroll
        for (int i = 0; i < 9; ++i) {
            int flat = tid + 256 * i;
            int row = flat / 144;
            int c4  = flat - row * 144;
            *(float4*)(kt + row * STR + 4 * c4) =
                *(const float4*)(K + (long)(sc8 * 16 + row) * D_ + 4 * c4);
        }
        __syncthreads();

        // ---- logits: 4h x 4s register tile over a 36-float d-slice ----
        float c[4][4];
#pragma unroll
        for (int i = 0; i < 4; ++i)
#pragma unroll
            for (int jj = 0; jj < 4; ++jj) c[i][jj] = 0.f;

#pragma unroll
        for (int j = 0; j < 9; ++j) {
            float4 qv[4], kv[4];
#pragma unroll
            for (int i = 0; i < 4; ++i)
                qv[i] = *(const float4*)(q_s + (4 * hq + i) * STR + dbase + 4 * j);
#pragma unroll
            for (int i = 0; i < 4; ++i)
                kv[i] = *(const float4*)(kt + (4 * sq + i) * STR + dbase + 4 * j);
#pragma unroll
            for (int i = 0; i < 4; ++i)
#pragma unroll
                for (int jj = 0; jj < 4; ++jj)
                    c[i][jj] += qv[i].x * kv[jj].x + qv[i].y * kv[jj].y +
                                qv[i].z * kv[jj].z + qv[i].w * kv[jj].w;
        }
        // reduce 4 dgrps within wave (lane bits 4,5)
#pragma unroll
        for (int i = 0; i < 4; ++i)
#pragma unroll
            for (int jj = 0; jj < 4; ++jj) {
                float v = c[i][jj];
                v += __shfl_xor(v, 16);
                v += __shfl_xor(v, 32);
                c[i][jj] = v;
            }
        if (sl < 16) {
#pragma unroll
            for (int i = 0; i < 4; ++i)
#pragma unroll
                for (int jj = 0; jj < 4; ++jj)
                    red[hg * 256 + sl * 16 + i * 4 + jj] = c[i][jj];
        }
        __syncthreads();

        // ---- gather logit in owning lane, online softmax ----
        float logit = bias[sc8];
        {
            const int rbase = (4 * hg + (s16 >> 2)) * 16 + h2 * 4 + (s16 & 3);
#pragma unroll
            for (int w = 0; w < 4; ++w) logit += red[w * 256 + rbase];
        }
        float mc = logit;
#pragma unroll
        for (int off = 1; off < 16; off <<= 1) mc = fmaxf(mc, __shfl_xor(mc, off));
        float m_new = fmaxf(m_run, mc);
        float alpha = __expf(m_run - m_new);
        float p = __expf(logit - m_new);
        float psum = p;
#pragma unroll
        for (int off = 1; off < 16; off <<= 1) psum += __shfl_xor(psum, off);
        l_run = l_run * alpha + psum;
        m_run = m_new;
        p_s[h * 16 + s16] = p;
        if (s16 == 0) alpha_s[h] = alpha;
        __syncthreads();

        // ---- PV: rescale accumulators, accumulate this chunk ----
        float a[4];
#pragma unroll
        for (int i = 0; i < 4; ++i) a[i] = alpha_s[4 * hg + i];
#pragma unroll
        for (int i = 0; i < 4; ++i) {
            oa0[i].x *= a[i]; oa0[i].y *= a[i]; oa0[i].z *= a[i]; oa0[i].w *= a[i];
            oa1[i].x *= a[i]; oa1[i].y *= a[i]; oa1[i].z *= a[i]; oa1[i].w *= a[i];
        }
#pragma unroll
        for (int s4 = 0; s4 < 4; ++s4) {
            float4 pf[4];
#pragma unroll
            for (int i = 0; i < 4; ++i)
                pf[i] = *(const float4*)(p_s + (4 * hg + i) * 16 + 4 * s4);
#pragma unroll
            for (int jj = 0; jj < 4; ++jj) {
                int s = 4 * s4 + jj;
                float4 v0 = *(const float4*)(kt + s * STR + 4 * sl);
                float4 v1 = *(const float4*)(kt + s * STR + 256 + 4 * sl);
#pragma unroll
                for (int i = 0; i < 4; ++i) {
                    const float* pfp = (const float*)&pf[i];
                    float pv = pfp[jj];
                    oa0[i].x += pv * v0.x; oa0[i].y += pv * v0.y;
                    oa0[i].z += pv * v0.z; oa0[i].w += pv * v0.w;
                    oa1[i].x += pv * v1.x; oa1[i].y += pv * v1.y;
                    oa1[i].z += pv * v1.z; oa1[i].w += pv * v1.w;
                }
            }
        }
    }

    // ---- epilogue: per-block stats + unscaled o ----
    if (s16 == 0) {
        g_bm[n * H_ + h] = m_run;
        g_bs[n * H_ + h] = l_run;
    }
    float* op = g_o + (long)n * H_ * KV_;
#pragma unroll
    for (int i = 0; i < 4; ++i) {
        *(float4*)(op + (4 * hg + i) * KV_ + 4 * sl) = oa0[i];
        *(float4*)(op + (4 * hg + i) * KV_ + 256 + 4 * sl) = oa1[i];
    }
}

// One workgroup per (b,h). Group combine: rescale each block's o and sum.
__global__ __launch_bounds__(128) void mla_combine_kernel(float* __restrict__ out)
{
    const int bh = blockIdx.x;
    const int b = bh >> 4;
    const int h = bh & 15;
    const int tid = threadIdx.x;

    float bm[16];
    float m = -1e30f;
#pragma unroll
    for (int j = 0; j < 16; ++j) {
        bm[j] = g_bm[(16 * b + j) * H_ + h];
        m = fmaxf(m, bm[j]);
    }
    float sa[16];
    float gs = 0.f;
#pragma unroll
    for (int j = 0; j < 16; ++j) {
        sa[j] = g_bs[(16 * b + j) * H_ + h] * __expf(bm[j] - m);
        gs += sa[j];
    }
    float4 acc = make_float4(0.f, 0.f, 0.f, 0.f);
#pragma unroll
    for (int j = 0; j < 16; ++j) {
        float r = __expf(bm[j] - m) / fmaxf(gs, sa[j]);
        const float4 v = *(const float4*)(g_o + ((long)((16 * b + j) * H_ + h)) * KV_ + 4 * tid);
        acc.x += r * v.x; acc.y += r * v.y;
        acc.z += r * v.z; acc.w += r * v.w;
    }
    *(float4*)(out + (long)bh * KV_ + 4 * tid) = acc;
}

extern "C" void kernel_launch(void* const* d_in, const int* in_sizes, int n_in,
                              void* d_out, int out_size, void* d_ws, size_t ws_size,
                              hipStream_t stream)
{
    const float* query        = (const float*)d_in[0];
    const float* key_cache    = (const float*)d_in[1];
    // d_in[2] = block_mapping (one-hot of block_groups) — not needed
    const float* block_bias   = (const float*)d_in[3];
    const int*   block_list   = (const int*)d_in[4];
    const int*   block_groups = (const int*)d_in[5];
    float* out = (float*)d_out;

    mla_block_kernel<<<NB_, 256, 0, stream>>>(query, key_cache, block_bias,
                                              block_list, block_groups);
    mla_combine_kernel<<<B_ * H_, 128, 0, stream>>>(out);
}

// Round 4
// 391.905 us; speedup vs baseline: 1.0751x; 1.0751x over previous
//
#include <hip/hip_runtime.h>
#include <math.h>

#define NB_ 512
#define B_ 32
#define H_ 16
#define D_ 576
#define KV_ 512
#define BS_ 128
#define SCALE_ 0.07216878364870323f   // 192^-0.5

typedef __attribute__((ext_vector_type(8))) short bf16x8;
typedef __attribute__((ext_vector_type(4))) float f32x4;

// Workspace as device globals: k1 fully writes before k2 reads, every call.
__device__ float g_o[NB_ * H_ * KV_];   // unscaled per-block output, 16.8 MB
__device__ float g_bm[NB_ * H_];        // per-block max
__device__ float g_bs[NB_ * H_];        // per-block sum

// float -> bf16 bits, round-to-nearest-even
static __device__ inline unsigned short f2bf(float f) {
    unsigned int u = __float_as_uint(f);
    unsigned int r = (u + 0x7FFFu + ((u >> 16) & 1u)) >> 16;
    return (unsigned short)r;
}

// One workgroup per block n. 256 threads = 4 waves.
// Phase 1: attn = q·K^T on bf16 MFMA (wave w owns s-tiles 2w, 2w+1, all 16 heads).
// Phase 2: o = p·V on fp32 VALU (wave w owns heads 4w..4w+3), R1 structure.
__global__ __launch_bounds__(256, 3) void mla_block_kernel(
    const float* __restrict__ query,
    const float* __restrict__ key_cache,
    const float* __restrict__ block_bias,
    const int* __restrict__ block_list,
    const int* __restrict__ block_groups)
{
    // region overlay:
    //   phase1: qf bf16[16][592]  bytes [0,18944)   (stride 592 bf16)
    //           kf bf16[128][72]  bytes [18944,37376) (stride 72 bf16, 64-d chunk)
    //   phase2: vt f32[16][512]   bytes [0,32768)
    //           p_s f32[16][128]  bytes [32768,40960)  (disjoint from phase1? no —
    //           kf tail overlaps p_s; p_s is written only after all kf reads done)
    __shared__ unsigned char region[40960];
    __shared__ float mred[4][16];
    __shared__ float lred[4][16];
    unsigned short* qf = (unsigned short*)region;
    unsigned short* kf = (unsigned short*)(region + 18944);
    float* vt  = (float*)region;
    float* p_s = (float*)(region + 32768);

    const int tid = threadIdx.x;
    const int n   = blockIdx.x;
    const int b   = block_groups[n];
    const float* K = key_cache + (long)block_list[n] * (BS_ * D_);
    const float* Q = query + (long)b * (H_ * D_);

    const int w    = tid >> 6;
    const int lane = tid & 63;
    const int a15  = lane & 15;
    const int q4   = lane >> 4;

    // ---- stage scaled q as bf16 into qf (16 rows x 144 float4) ----
#pragma unroll
    for (int i = 0; i < 9; ++i) {
        int flat = tid + 256 * i;           // 0..2303
        int row = flat / 144;
        int c4  = flat - row * 144;
        float4 v = *(const float4*)(Q + row * D_ + 4 * c4);
        ushort4 us;
        us.x = f2bf(v.x * SCALE_); us.y = f2bf(v.y * SCALE_);
        us.z = f2bf(v.z * SCALE_); us.w = f2bf(v.w * SCALE_);
        *(ushort4*)(qf + row * 592 + 4 * c4) = us;
    }

    // ---- phase 1: QK^T via MFMA, 9 chunks of 64 d ----
    f32x4 acc0 = {0.f, 0.f, 0.f, 0.f};
    f32x4 acc1 = {0.f, 0.f, 0.f, 0.f};
    for (int kk = 0; kk < 9; ++kk) {
        __syncthreads();   // prev chunk's kf reads done (1st iter: qf staged)
        // stage kf: 128 rows x 64 d as bf16 (2048 float4 / 256 thr)
#pragma unroll
        for (int i = 0; i < 8; ++i) {
            int flat = tid + 256 * i;       // 0..2047
            int s = flat >> 4;
            int bb = flat & 15;
            float4 v = *(const float4*)(K + (long)s * D_ + kk * 64 + 4 * bb);
            ushort4 us;
            us.x = f2bf(v.x); us.y = f2bf(v.y); us.z = f2bf(v.z); us.w = f2bf(v.w);
            *(ushort4*)(kf + s * 72 + 4 * bb) = us;
        }
        __syncthreads();
#pragma unroll
        for (int t = 0; t < 2; ++t) {
            bf16x8 af  = *(bf16x8*)(qf + a15 * 592 + kk * 64 + t * 32 + 8 * q4);
            bf16x8 bf0 = *(bf16x8*)(kf + (32 * w + a15) * 72 + t * 32 + 8 * q4);
            bf16x8 bf1 = *(bf16x8*)(kf + (32 * w + 16 + a15) * 72 + t * 32 + 8 * q4);
            acc0 = __builtin_amdgcn_mfma_f32_16x16x32_bf16(af, bf0, acc0, 0, 0, 0);
            acc1 = __builtin_amdgcn_mfma_f32_16x16x32_bf16(af, bf1, acc1, 0, 0, 0);
        }
    }

    // ---- softmax epilogue. C layout: col(s)=lane&15, row(h)=q4*4+r ----
    const float* bias = block_bias + n * BS_;
    float b0 = bias[32 * w + a15];
    float b1 = bias[32 * w + 16 + a15];
    float lg0[4], lg1[4], mw[4];
#pragma unroll
    for (int r = 0; r < 4; ++r) {
        lg0[r] = acc0[r] + b0;
        lg1[r] = acc1[r] + b1;
        float m = fmaxf(lg0[r], lg1[r]);
#pragma unroll
        for (int off = 1; off < 16; off <<= 1) m = fmaxf(m, __shfl_xor(m, off));
        mw[r] = m;
    }
    if (a15 == 0) {
#pragma unroll
        for (int r = 0; r < 4; ++r) mred[w][4 * q4 + r] = mw[r];
    }
    __syncthreads();   // also: all kf reads done -> p_s region safe to write
    float mg[4], lw[4];
#pragma unroll
    for (int r = 0; r < 4; ++r) {
        int h = 4 * q4 + r;
        float m = fmaxf(fmaxf(mred[0][h], mred[1][h]), fmaxf(mred[2][h], mred[3][h]));
        mg[r] = m;
        float p0 = __expf(lg0[r] - m);
        float p1 = __expf(lg1[r] - m);
        p_s[h * BS_ + 32 * w + a15]      = p0;
        p_s[h * BS_ + 32 * w + 16 + a15] = p1;
        float s = p0 + p1;
#pragma unroll
        for (int off = 1; off < 16; off <<= 1) s += __shfl_xor(s, off);
        lw[r] = s;
    }
    if (a15 == 0) {
#pragma unroll
        for (int r = 0; r < 4; ++r) lred[w][4 * q4 + r] = lw[r];
    }
    __syncthreads();   // p_s + lred visible to all
    if (w == 0 && a15 == 0) {
#pragma unroll
        for (int r = 0; r < 4; ++r) {
            int h = 4 * q4 + r;
            g_bm[n * H_ + h] = mg[r];
            g_bs[n * H_ + h] = lred[0][h] + lred[1][h] + lred[2][h] + lred[3][h];
        }
    }

    // ---- phase 2: o = p @ V, V streamed in s-chunks of 16 (fp32, R1 structure) ----
    const int hg = w;
    const int sl = lane;
    float4 oa0[4], oa1[4];
#pragma unroll
    for (int i = 0; i < 4; ++i) {
        oa0[i] = make_float4(0.f, 0.f, 0.f, 0.f);
        oa1[i] = make_float4(0.f, 0.f, 0.f, 0.f);
    }
    for (int sc = 0; sc < 8; ++sc) {
        __syncthreads();   // prev tile reads done; 1st iter: epilogue done (vt overwrites qf/kf)
#pragma unroll
        for (int i = 0; i < 8; ++i) {
            int flat = tid + 256 * i;           // 2048 float4 = 16 rows x 128
            int s = flat >> 7;
            int c = (flat & 127) << 2;
            *(float4*)(vt + s * KV_ + c) = *(const float4*)(K + (long)(16 * sc + s) * D_ + c);
        }
        __syncthreads();
#pragma unroll 4
        for (int s = 0; s < 16; ++s) {
            float4 v0 = *(const float4*)(vt + s * KV_ + 4 * sl);
            float4 v1 = *(const float4*)(vt + s * KV_ + 256 + 4 * sl);
#pragma unroll
            for (int i = 0; i < 4; ++i) {
                float pv = p_s[(4 * hg + i) * BS_ + 16 * sc + s];
                oa0[i].x += pv * v0.x; oa0[i].y += pv * v0.y;
                oa0[i].z += pv * v0.z; oa0[i].w += pv * v0.w;
                oa1[i].x += pv * v1.x; oa1[i].y += pv * v1.y;
                oa1[i].z += pv * v1.z; oa1[i].w += pv * v1.w;
            }
        }
    }

    // ---- write unscaled o ----
    float* op = g_o + (long)n * H_ * KV_;
#pragma unroll
    for (int i = 0; i < 4; ++i) {
        *(float4*)(op + (4 * hg + i) * KV_ + 4 * sl) = oa0[i];
        *(float4*)(op + (4 * hg + i) * KV_ + 256 + 4 * sl) = oa1[i];
    }
}

// One workgroup per (b,h). Group combine: rescale each block's o and sum.
__global__ __launch_bounds__(128) void mla_combine_kernel(float* __restrict__ out)
{
    const int bh = blockIdx.x;
    const int b = bh >> 4;
    const int h = bh & 15;
    const int tid = threadIdx.x;

    float bm[16];
    float m = -1e30f;
#pragma unroll
    for (int j = 0; j < 16; ++j) {
        bm[j] = g_bm[(16 * b + j) * H_ + h];
        m = fmaxf(m, bm[j]);
    }
    float sa[16];
    float gs = 0.f;
#pragma unroll
    for (int j = 0; j < 16; ++j) {
        sa[j] = g_bs[(16 * b + j) * H_ + h] * __expf(bm[j] - m);
        gs += sa[j];
    }
    float4 acc = make_float4(0.f, 0.f, 0.f, 0.f);
#pragma unroll
    for (int j = 0; j < 16; ++j) {
        float r = __expf(bm[j] - m) / fmaxf(gs, sa[j]);
        const float4 v = *(const float4*)(g_o + ((long)((16 * b + j) * H_ + h)) * KV_ + 4 * tid);
        acc.x += r * v.x; acc.y += r * v.y;
        acc.z += r * v.z; acc.w += r * v.w;
    }
    *(float4*)(out + (long)bh * KV_ + 4 * tid) = acc;
}

extern "C" void kernel_launch(void* const* d_in, const int* in_sizes, int n_in,
                              void* d_out, int out_size, void* d_ws, size_t ws_size,
                              hipStream_t stream)
{
    const float* query        = (const float*)d_in[0];
    const float* key_cache    = (const float*)d_in[1];
    // d_in[2] = block_mapping (one-hot of block_groups) — not needed
    const float* block_bias   = (const float*)d_in[3];
    const int*   block_list   = (const int*)d_in[4];
    const int*   block_groups = (const int*)d_in[5];
    float* out = (float*)d_out;

    mla_block_kernel<<<NB_, 256, 0, stream>>>(query, key_cache, block_bias,
                                              block_list, block_groups);
    mla_combine_kernel<<<B_ * H_, 128, 0, stream>>>(out);
}